// Round 13
// baseline (45.097 us; speedup 1.0000x reference)
//
#include <hip/hip_runtime.h>

#define B_ 4
#define C_ 64
#define H_ 128
#define W_ 128
#define O_ 64
#define KK_ 9
#define OFFC_ 18
#define HW_ (H_*W_)
#define VSB 1152   // val row stride in bytes (576 fp16)

typedef __attribute__((ext_vector_type(8))) _Float16 h8;
typedef __attribute__((ext_vector_type(4))) _Float16 h4;
typedef __attribute__((ext_vector_type(4))) float f32x4;

// ---------- kernel 1: transpose x NCHW fp32 -> NHWC fp16, + weight prep ----------
__global__ __launch_bounds__(256) void k_pre(
    const float* __restrict__ x, const float* __restrict__ w_dcn,
    const float* __restrict__ w_off, _Float16* __restrict__ xt,
    _Float16* __restrict__ wb, _Float16* __restrict__ wboff)
{
    __shared__ float tile[C_][133];
    int blk = blockIdx.x;
    if (blk < 512) {
        const float* xp = x + (size_t)(blk >> 7) * C_ * HW_ + (blk & 127) * W_;
#pragma unroll
        for (int i = 0; i < 8; ++i) {
            int idx = threadIdx.x + i * 256;     // 0..2047 float4 slots
            int c = idx >> 5, w4 = idx & 31;
            float4 v = *(const float4*)(xp + c * HW_ + w4 * 4);
            tile[c][w4*4+0] = v.x; tile[c][w4*4+1] = v.y;
            tile[c][w4*4+2] = v.z; tile[c][w4*4+3] = v.w;
        }
        __syncthreads();
        _Float16* op = xt + (size_t)blk * (W_ * C_);
#pragma unroll
        for (int i = 0; i < 8; ++i) {
            int idx = threadIdx.x + i * 256;     // 0..2047 h4 slots
            int w = idx >> 4, c4 = idx & 15;
            h4 o;
            o.x = (_Float16)tile[c4*4+0][w]; o.y = (_Float16)tile[c4*4+1][w];
            o.z = (_Float16)tile[c4*4+2][w]; o.w = (_Float16)tile[c4*4+3][w];
            *(h4*)(op + w*64 + c4*4) = o;
        }
    } else {
        int i = (blk - 512) * 256 + threadIdx.x;
        if (i < O_ * 576) {
            int j = i & 7, l = (i >> 3) & 63, t = (i >> 9) % 18, ot = i / (18*512);
            int k = t*32 + ((l>>4)&3)*8 + j;
            int o = ot*16 + (l & 15);
            int kk = k >> 6, c = k & 63;
            wb[i] = (_Float16)w_dcn[(o*64 + c)*9 + kk];
        }
        int i2 = i - O_*576;
        if (i2 >= 0 && i2 < 32*576) {
            int j = i2 & 7, l = (i2 >> 3) & 63, t = (i2 >> 9) % 18, mt = i2 / (18*512);
            int k = t*32 + ((l>>4)&3)*8 + j;
            int o = mt*16 + (l & 15);
            int kk = k >> 6, c = k & 63;
            wboff[i2] = (o < OFFC_) ? (_Float16)w_off[(o*64 + c)*9 + kk] : (_Float16)0.f;
        }
    }
}

// ---------- kernel 2: fused offset-conv + deformable conv, 16-px 2-wave blocks ----------
// grid = B*H*8 = 4096, XCD-swizzled (512 blocks/XCD = 64 rows of one batch).
// 128 threads = 2 waves: barriers sync only 2 waves; LDS 19.7 KB -> 8 blocks/CU
// resident (16 waves/CU at VGPR<=128 via launch_bounds(128,4)).
__global__ __launch_bounds__(128, 4) void k_fused(
    const _Float16* __restrict__ xt, const _Float16* __restrict__ wb,
    const _Float16* __restrict__ wboff, const float* __restrict__ b_off,
    const float* __restrict__ b_dcn, float* __restrict__ out)
{
    __shared__ __align__(16) char val[16 * VSB];      // 18432 B
    __shared__ __align__(16) float offl[OFFC_][17];   // 1224 B (padded)

    int tid = threadIdx.x;
    int d = blockIdx.x;
    int blk = (d & 7) * 512 + (d >> 3);   // XCD-contiguous chunks
    int wt = blk & 7, ho = (blk >> 3) & 127, b = blk >> 10;
    int wo0 = wt * 16;
    int wave = tid >> 6, lane = tid & 63;
    const char* xbc = (const char*)xt + (size_t)b * HW_ * 128;

    int cg8 = tid & 7, p = tid >> 3;      // gather roles: pixel p, channel-slice cg8
    int ph = p & 7;
    char* vb = val + p * VSB;

    // ---- P0: regular im2col gather for offset conv -> val ----
    {
        int wo = wo0 + p;
#pragma unroll 3
        for (int kk = 0; kk < KK_; ++kk) {
            int y = ho + kk/3 - 1;
            int xx = wo + kk%3 - 1;
            h8 v = {0,0,0,0,0,0,0,0};
            if ((unsigned)y < H_ && (unsigned)xx < W_)
                v = *(const h8*)(xbc + (y*W_ + xx)*128 + cg8*16);
            *(h8*)(vb + (((kk*8 + cg8) ^ ph) << 4)) = v;
        }
    }
    __syncthreads();

    // ---- P1: offset MFMA, wave = M-tile (0: ch 0-15, 1: ch 16-17) ----
    {
        h8 aoff[18];
        const _Float16* wp = wboff + ((wave*18)*64 + lane)*8;
#pragma unroll
        for (int t = 0; t < 18; ++t) aoff[t] = *(const h8*)(wp + t*512);
        f32x4 acc = {0.f,0.f,0.f,0.f};
        const char* vrd = val + (lane & 15) * VSB;
        int gk = (lane >> 4) & 3;
        int phm = (lane & 15) & 7;
#pragma unroll
        for (int t = 0; t < 18; ++t) {
            h8 bfr = *(const h8*)(vrd + (((t*4 + gk) ^ phm) << 4));
            acc = __builtin_amdgcn_mfma_f32_16x16x32_f16(aoff[t], bfr, acc, 0, 0, 0);
        }
        int orow = wave*16 + gk*4;
#pragma unroll
        for (int r = 0; r < 4; ++r) {
            int o = orow + r;
            if (o < OFFC_)
                offl[o][lane & 15] = acc[r] + b_off[o];
        }
    }
    __syncthreads();

    // ---- P3: pos-compute + bilinear gather + packed fp16 blend -> val ----
    {
        int wo = wo0 + p;
#pragma unroll 3
        for (int kk = 0; kk < KK_; ++kk) {
            float dy = offl[2*kk  ][p];
            float dx = offl[2*kk+1][p];
            float py = (float)(ho - 1 + kk/3) + dy;
            float px = (float)(wo - 1 + kk%3) + dx;
            float fy = floorf(py), fx = floorf(px);
            int y0 = (int)fy, x0 = (int)fx;
            float ly = py - fy, lx = px - fx;
            int y1 = y0 + 1, x1 = x0 + 1;
            float my0 = ((unsigned)y0 < H_) ? 1.f : 0.f;
            float my1 = ((unsigned)y1 < H_) ? 1.f : 0.f;
            float mx0 = ((unsigned)x0 < W_) ? 1.f : 0.f;
            float mx1 = ((unsigned)x1 < W_) ? 1.f : 0.f;
            int y0c = min(max(y0,0),H_-1), y1c = min(max(y1,0),H_-1);
            int x0c = min(max(x0,0),W_-1), x1c = min(max(x1,0),W_-1);
            h8 c0 = *(const h8*)(xbc + (y0c*W_ + x0c)*128 + cg8*16);
            h8 c1 = *(const h8*)(xbc + (y0c*W_ + x1c)*128 + cg8*16);
            h8 c2 = *(const h8*)(xbc + (y1c*W_ + x0c)*128 + cg8*16);
            h8 c3 = *(const h8*)(xbc + (y1c*W_ + x1c)*128 + cg8*16);
            _Float16 h00 = (_Float16)((1.f-ly)*(1.f-lx)*my0*mx0);
            _Float16 h01 = (_Float16)((1.f-ly)*lx*my0*mx1);
            _Float16 h10 = (_Float16)(ly*(1.f-lx)*my1*mx0);
            _Float16 h11 = (_Float16)(ly*lx*my1*mx1);
            h8 w00v = {h00,h00,h00,h00,h00,h00,h00,h00};
            h8 w01v = {h01,h01,h01,h01,h01,h01,h01,h01};
            h8 w10v = {h10,h10,h10,h10,h10,h10,h10,h10};
            h8 w11v = {h11,h11,h11,h11,h11,h11,h11,h11};
            h8 r = c0*w00v + c1*w01v + c2*w10v + c3*w11v;
            *(h8*)(vb + (((kk*8 + cg8) ^ ph) << 4)) = r;
        }
    }
    __syncthreads();

    // ---- P4: deform MFMA, wave w does ch-tiles {w, w+2} sequentially ----
    {
        int gk = (lane >> 4) & 3;
        int phm = (lane & 15) & 7;
        const char* vrd = val + (lane & 15) * VSB;
        int wo = wo0 + (lane & 15);
#pragma unroll
        for (int i = 0; i < 2; ++i) {
            int ot = wave + 2*i;
            h8 afr[18];
            const _Float16* wp = wb + ((ot*18)*64 + lane)*8;
#pragma unroll
            for (int t = 0; t < 18; ++t) afr[t] = *(const h8*)(wp + t*512);
            f32x4 acc = {0.f,0.f,0.f,0.f};
#pragma unroll
            for (int t = 0; t < 18; ++t) {
                h8 bfr = *(const h8*)(vrd + (((t*4 + gk) ^ phm) << 4));
                acc = __builtin_amdgcn_mfma_f32_16x16x32_f16(afr[t], bfr, acc, 0, 0, 0);
            }
            int orow = ot*16 + gk*4;
#pragma unroll
            for (int r = 0; r < 4; ++r) {
                int o = orow + r;
                out[((b*O_ + o)*H_ + ho)*W_ + wo] = acc[r] + b_dcn[o];
            }
        }
    }
}

extern "C" void kernel_launch(void* const* d_in, const int* in_sizes, int n_in,
                              void* d_out, int out_size, void* d_ws, size_t ws_size,
                              hipStream_t stream) {
    const float* x     = (const float*)d_in[0];
    const float* w_off = (const float*)d_in[1];
    const float* b_off = (const float*)d_in[2];
    const float* w_dcn = (const float*)d_in[3];
    const float* b_dcn = (const float*)d_in[4];
    float* out = (float*)d_out;

    char* ws = (char*)d_ws;
    _Float16* xt   = (_Float16*)ws;                          // 8,388,608 B
    _Float16* wb   = (_Float16*)(ws + 8388608);              // 73,728 B
    _Float16* wboff = wb + O_*576;                           // 36,864 B

    k_pre<<<728, 256, 0, stream>>>(x, w_dcn, w_off, xt, wb, wboff);
    k_fused<<<B_ * H_ * 8, 128, 0, stream>>>(xt, wb, wboff, b_off, b_dcn, out);
}

// Round 14
// 40.161 us; speedup vs baseline: 1.1229x; 1.1229x over previous
//
#include <hip/hip_runtime.h>

#define B_ 4
#define C_ 64
#define H_ 128
#define W_ 128
#define O_ 64
#define KK_ 9
#define OFFC_ 18
#define HW_ (H_*W_)
#define VSB 1152   // val row stride in bytes (576 fp16)

typedef __attribute__((ext_vector_type(8))) _Float16 h8;
typedef __attribute__((ext_vector_type(4))) _Float16 h4;
typedef __attribute__((ext_vector_type(4))) float f32x4;

// ---------- kernel 1: transpose x NCHW fp32 -> NHWC fp16, + weight prep ----------
__global__ __launch_bounds__(256) void k_pre(
    const float* __restrict__ x, const float* __restrict__ w_dcn,
    const float* __restrict__ w_off, _Float16* __restrict__ xt,
    _Float16* __restrict__ wb, _Float16* __restrict__ wboff)
{
    __shared__ float tile[C_][133];
    int blk = blockIdx.x;
    if (blk < 512) {
        const float* xp = x + (size_t)(blk >> 7) * C_ * HW_ + (blk & 127) * W_;
#pragma unroll
        for (int i = 0; i < 8; ++i) {
            int idx = threadIdx.x + i * 256;     // 0..2047 float4 slots
            int c = idx >> 5, w4 = idx & 31;
            float4 v = *(const float4*)(xp + c * HW_ + w4 * 4);
            tile[c][w4*4+0] = v.x; tile[c][w4*4+1] = v.y;
            tile[c][w4*4+2] = v.z; tile[c][w4*4+3] = v.w;
        }
        __syncthreads();
        _Float16* op = xt + (size_t)blk * (W_ * C_);
#pragma unroll
        for (int i = 0; i < 8; ++i) {
            int idx = threadIdx.x + i * 256;     // 0..2047 h4 slots
            int w = idx >> 4, c4 = idx & 15;
            h4 o;
            o.x = (_Float16)tile[c4*4+0][w]; o.y = (_Float16)tile[c4*4+1][w];
            o.z = (_Float16)tile[c4*4+2][w]; o.w = (_Float16)tile[c4*4+3][w];
            *(h4*)(op + w*64 + c4*4) = o;
        }
    } else {
        int i = (blk - 512) * 256 + threadIdx.x;
        if (i < O_ * 576) {
            int j = i & 7, l = (i >> 3) & 63, t = (i >> 9) % 18, ot = i / (18*512);
            int k = t*32 + ((l>>4)&3)*8 + j;
            int o = ot*16 + (l & 15);
            int kk = k >> 6, c = k & 63;
            wb[i] = (_Float16)w_dcn[(o*64 + c)*9 + kk];
        }
        int i2 = i - O_*576;
        if (i2 >= 0 && i2 < 32*576) {
            int j = i2 & 7, l = (i2 >> 3) & 63, t = (i2 >> 9) % 18, mt = i2 / (18*512);
            int k = t*32 + ((l>>4)&3)*8 + j;
            int o = mt*16 + (l & 15);
            int kk = k >> 6, c = k & 63;
            wboff[i2] = (o < OFFC_) ? (_Float16)w_off[(o*64 + c)*9 + kk] : (_Float16)0.f;
        }
    }
}

// ---------- kernel 2: fused offset-conv + deformable conv, 32-px blocks ----------
// grid = B*H*4 = 2048, XCD-swizzled. LDS 39.2 KB -> 4 blocks/CU;
// launch_bounds(256,4) caps VGPR at 128 -> 4 waves/SIMD.
// P3 batches 3 taps: 12 loads issued before any blend.
__global__ __launch_bounds__(256, 4) void k_fused(
    const _Float16* __restrict__ xt, const _Float16* __restrict__ wb,
    const _Float16* __restrict__ wboff, const float* __restrict__ b_off,
    const float* __restrict__ b_dcn, float* __restrict__ out)
{
    __shared__ __align__(16) char val2[2][16 * VSB];    // 36864 B
    __shared__ __align__(16) float offl[OFFC_][32];     // 2304 B

    int tid = threadIdx.x;
    int d = blockIdx.x;
    int blk = (d & 7) * 256 + (d >> 3);   // XCD-contiguous chunks
    int wt2 = blk & 3, ho = (blk >> 2) & 127, b = blk >> 9;
    int wo0 = wt2 * 32;
    int wave = tid >> 6, lane = tid & 63;
    int mt = wave >> 1;          // M-tile for offset MFMA
    int rg_m = wave & 1;         // px region for offset MFMA
    const char* xbc = (const char*)xt + (size_t)b * HW_ * 128;

    // ---- P0: regular im2col gather for offset conv -> val2 ----
    {
        int cg8 = tid & 7, px32 = tid >> 3;
        int rg_f = px32 >> 4, p = px32 & 15, ph = p & 7;
        char* vb = &val2[rg_f][0] + p * VSB;
        int wo = wo0 + px32;
#pragma unroll 3
        for (int kk = 0; kk < KK_; ++kk) {
            int y = ho + kk/3 - 1;
            int xx = wo + kk%3 - 1;
            h8 v = {0,0,0,0,0,0,0,0};
            if ((unsigned)y < H_ && (unsigned)xx < W_)
                v = *(const h8*)(xbc + (y*W_ + xx)*128 + cg8*16);
            int g8 = kk*8 + cg8;
            *(h8*)(vb + ((g8 ^ ph) << 4)) = v;
        }
    }
    __syncthreads();

    // ---- P1: offset MFMA, wave=(mt,rg) -> offl ----
    {
        h8 aoff[18];
        const _Float16* wp = wboff + ((mt*18)*64 + lane)*8;
#pragma unroll
        for (int t = 0; t < 18; ++t) aoff[t] = *(const h8*)(wp + t*512);
        f32x4 acc = {0.f,0.f,0.f,0.f};
        const char* vb = &val2[rg_m][0] + (lane & 15) * VSB;
        int gk = (lane >> 4) & 3;
        int ph = (lane & 15) & 7;
#pragma unroll
        for (int t = 0; t < 18; ++t) {
            h8 bfr = *(const h8*)(vb + (((t*4 + gk) ^ ph) << 4));
            acc = __builtin_amdgcn_mfma_f32_16x16x32_f16(aoff[t], bfr, acc, 0, 0, 0);
        }
        int orow = mt*16 + gk*4;
#pragma unroll
        for (int r = 0; r < 4; ++r) {
            int o = orow + r;
            if (o < OFFC_)
                offl[o][rg_m*16 + (lane & 15)] = acc[r] + b_off[o];
        }
    }
    __syncthreads();

    // ---- P3: pos-compute + bilinear gather, batched 3 taps (12 loads in flight) ----
    {
        int cg8 = tid & 7, p = (tid >> 3) & 31;
        int ph = p & 7;
        char* vb = &val2[p >> 4][0] + (p & 15) * VSB;
        int wo = wo0 + p;
        for (int kb = 0; kb < 3; ++kb) {      // runtime loop: bounds VGPR
            h8 cc[3][4];
            _Float16 hw[3][4];
            int so[3];
#pragma unroll
            for (int j = 0; j < 3; ++j) {
                int kk = kb*3 + j;            // kk/3 == kb, kk%3 == j
                float dy = offl[2*kk  ][p];
                float dx = offl[2*kk+1][p];
                float py = (float)(ho - 1 + kb) + dy;
                float px = (float)(wo - 1 + j) + dx;
                float fy = floorf(py), fx = floorf(px);
                int y0 = (int)fy, x0 = (int)fx;
                float ly = py - fy, lx = px - fx;
                int y1 = y0 + 1, x1 = x0 + 1;
                float my0 = ((unsigned)y0 < H_) ? 1.f : 0.f;
                float my1 = ((unsigned)y1 < H_) ? 1.f : 0.f;
                float mx0 = ((unsigned)x0 < W_) ? 1.f : 0.f;
                float mx1 = ((unsigned)x1 < W_) ? 1.f : 0.f;
                int y0c = min(max(y0,0),H_-1), y1c = min(max(y1,0),H_-1);
                int x0c = min(max(x0,0),W_-1), x1c = min(max(x1,0),W_-1);
                cc[j][0] = *(const h8*)(xbc + (y0c*W_ + x0c)*128 + cg8*16);
                cc[j][1] = *(const h8*)(xbc + (y0c*W_ + x1c)*128 + cg8*16);
                cc[j][2] = *(const h8*)(xbc + (y1c*W_ + x0c)*128 + cg8*16);
                cc[j][3] = *(const h8*)(xbc + (y1c*W_ + x1c)*128 + cg8*16);
                hw[j][0] = (_Float16)((1.f-ly)*(1.f-lx)*my0*mx0);
                hw[j][1] = (_Float16)((1.f-ly)*lx*my0*mx1);
                hw[j][2] = (_Float16)(ly*(1.f-lx)*my1*mx0);
                hw[j][3] = (_Float16)(ly*lx*my1*mx1);
                so[j] = ((kk*8 + cg8) ^ ph) << 4;
            }
#pragma unroll
            for (int j = 0; j < 3; ++j) {
                _Float16 h00 = hw[j][0], h01 = hw[j][1];
                _Float16 h10 = hw[j][2], h11 = hw[j][3];
                h8 w00v = {h00,h00,h00,h00,h00,h00,h00,h00};
                h8 w01v = {h01,h01,h01,h01,h01,h01,h01,h01};
                h8 w10v = {h10,h10,h10,h10,h10,h10,h10,h10};
                h8 w11v = {h11,h11,h11,h11,h11,h11,h11,h11};
                h8 r = cc[j][0]*w00v + cc[j][1]*w01v + cc[j][2]*w10v + cc[j][3]*w11v;
                *(h8*)(vb + so[j]) = r;
            }
        }
    }
    __syncthreads();

    // ---- P4: deform MFMA, wave w owns ch w*16..w*16+15, both px regions ----
    {
        h8 afr[18];
        const _Float16* wp = wb + ((wave*18)*64 + lane)*8;
#pragma unroll
        for (int t = 0; t < 18; ++t) afr[t] = *(const h8*)(wp + t*512);
        int gk = (lane >> 4) & 3;
        int ph = (lane & 15) & 7;
        int orow = wave*16 + gk*4;
#pragma unroll
        for (int rg = 0; rg < 2; ++rg) {
            f32x4 acc = {0.f,0.f,0.f,0.f};
            const char* vb = &val2[rg][0] + (lane & 15) * VSB;
#pragma unroll
            for (int t = 0; t < 18; ++t) {
                h8 bfr = *(const h8*)(vb + (((t*4 + gk) ^ ph) << 4));
                acc = __builtin_amdgcn_mfma_f32_16x16x32_f16(afr[t], bfr, acc, 0, 0, 0);
            }
            int wo = wo0 + rg*16 + (lane & 15);
#pragma unroll
            for (int r = 0; r < 4; ++r) {
                int o = orow + r;
                out[((b*O_ + o)*H_ + ho)*W_ + wo] = acc[r] + b_dcn[o];
            }
        }
    }
}

extern "C" void kernel_launch(void* const* d_in, const int* in_sizes, int n_in,
                              void* d_out, int out_size, void* d_ws, size_t ws_size,
                              hipStream_t stream) {
    const float* x     = (const float*)d_in[0];
    const float* w_off = (const float*)d_in[1];
    const float* b_off = (const float*)d_in[2];
    const float* w_dcn = (const float*)d_in[3];
    const float* b_dcn = (const float*)d_in[4];
    float* out = (float*)d_out;

    char* ws = (char*)d_ws;
    _Float16* xt   = (_Float16*)ws;                          // 8,388,608 B
    _Float16* wb   = (_Float16*)(ws + 8388608);              // 73,728 B
    _Float16* wboff = wb + O_*576;                           // 36,864 B

    k_pre<<<728, 256, 0, stream>>>(x, w_dcn, w_off, xt, wb, wboff);
    k_fused<<<B_ * H_ * 4, 256, 0, stream>>>(xt, wb, wboff, b_off, b_dcn, out);
}